// Round 7
// baseline (88.216 us; speedup 1.0000x reference)
//
#include <hip/hip_runtime.h>

// Wave forward: 16 channels, 208x208 window/channel, 48 steps, ONE persistent
// kernel. 6 phases x 8 substeps; boundaries sync the 3x3 tile neighborhood via
// agent-scope atomic flags; data moves as packed float2 via 64-bit relaxed
// agent atomics. blockIdx remapped so each channel's 16 tiles share one XCD
// (b%8 round-robin) -> halo traffic is L2-local. Liveness (support cone) gates
// publish/spin/pull. Register-blocked 4x4 cells/thread; LDS ping-pong.

typedef unsigned long long u64;

#define GN     512
#define NMASK  511
#define NCH    16
#define NT     48
#define NM     128
#define WW     208            // window size
#define WOFF   103            // source offset inside window
#define TI     52             // tile interior
#define TS     8              // substeps per phase
#define NPHASE 6
#define HALO   16             // 2*TS
#define LT     84             // tile width (TI + 2*HALO)
#define LTS    84             // LDS row stride
#define LDSE   (LTS*LT)       // 7056
#define WCELLS (WW*WW)        // 43264
#define NTH    448            // 7 waves
#define NACT   441            // 21x21 threads x 4x4 cells = 84^2
#define NBLK   256
#define FRAME_N 2304          // interior rim cells (52^2 - 20^2)
#define FRAME_A 1664          // rows 16-31,52-67 x cols 16-67
#define HALO_N  4352          // 84^2 - 52^2
#define HALO_TB 2688          // rows 0-15,68-83 x cols 0-83

__device__ __forceinline__ float4 ld4(const float* p) { return *(const float4*)p; }
__device__ __forceinline__ void st4(float* p, float4 v) { *(float4*)p = v; }

__device__ __forceinline__ float kcoef(const float* __restrict__ x, int gi, int gj) {
    float xp;
    if (gi < 55 || gi >= 457 || gj < 55 || gj >= 457)
        xp = 1e-6f;                                   // ABC pad
    else if (gi >= 128 && gi < 384 && gj >= 128 && gj < 384)
        xp = x[(gi - 128) * 256 + (gj - 128)];
    else
        xp = 1.5f;                                    // bg pad
    float t = 0.2f * xp;
    return t * t;
}

// support-cone distance of a tile's 84^2 region to the source (channel-indep.)
__device__ __forceinline__ int tile_sdist(int ti, int tj) {
    int lo = ti * TI - HALO, hi = lo + LT - 1;
    int di = WOFF < lo ? lo - WOFF : (WOFF > hi ? WOFF - hi : 0);
    lo = tj * TI - HALO; hi = lo + LT - 1;
    int dj = WOFF < lo ? lo - WOFF : (WOFF > hi ? WOFF - hi : 0);
    return di > dj ? di : dj;
}
__device__ __forceinline__ bool tile_live(int ti, int tj, int ph) {
    return tile_sdist(ti, tj) <= 2 * (ph * TS + TS) + 4;
}

__global__ __launch_bounds__(NTH, 1)
void persist_kernel(const float* __restrict__ x,
                    const float* __restrict__ src,
                    const int* __restrict__ meas,
                    const int* __restrict__ trans,
                    int* __restrict__ flags,
                    float2* __restrict__ GA, float2* __restrict__ GB,
                    float* __restrict__ out)
{
    __shared__ float lds0[LDSE];
    __shared__ float lds1[LDSE];
    const int tid  = threadIdx.x;
    const int b    = blockIdx.x;
    const int r    = b & 15;          // channel -> all its tiles share b%8 (XCD)
    const int tile = b >> 4;
    const int tI   = tile >> 2, tJ = tile & 3;
    const int ri0  = tI * TI - HALO;
    const int rj0  = tJ * TI - HALO;

    const bool active = tid < NACT;
    const int ty = tid / 21, tx = tid - 21 * (tid / 21);
    const int li0 = 4 * ty, lj0 = 4 * tx;
    const bool inner = active && tx >= 4 && tx <= 16 && ty >= 4 && ty <= 16;

    // zero BOTH buffers (dead->live blocks rely on pristine-zero LDS)
    for (int q = tid; q < LDSE / 4; q += NTH) {
        st4(&lds0[q * 4], make_float4(0.f, 0.f, 0.f, 0.f));
        st4(&lds1[q * 4], make_float4(0.f, 0.f, 0.f, 0.f));
    }

    const int trv = trans[r];
    const int ox = (trv >> 9) - WOFF, oy = (trv & NMASK) - WOFF;

    float C[16], P[16], K[16];
    #pragma unroll
    for (int i = 0; i < 16; ++i) { C[i] = 0.f; P[i] = 0.f; K[i] = 0.f; }

    int offT2 = 0, offT1 = 0, offB1 = 0, offB2 = 0;
    int offL[4] = {0,0,0,0}, offR[4] = {0,0,0,0}, offC[4] = {0,0,0,0};
    unsigned smask = 0;
    if (active) {
        #pragma unroll
        for (int rr = 0; rr < 4; ++rr) {
            int wr = ri0 + li0 + rr;
            #pragma unroll
            for (int cc = 0; cc < 4; ++cc) {
                int wc = rj0 + lj0 + cc;
                K[rr*4+cc] = kcoef(x, (ox + wr) & NMASK, (oy + wc) & NMASK);
            }
        }
        int rT2 = li0 - 2 < 0 ? 0 : li0 - 2;
        int rT1 = li0 - 1 < 0 ? 0 : li0 - 1;
        int rB1 = li0 + 4 > LT - 1 ? LT - 1 : li0 + 4;
        int rB2 = li0 + 5 > LT - 1 ? LT - 1 : li0 + 5;
        offT2 = rT2 * LTS + lj0;  offT1 = rT1 * LTS + lj0;
        offB1 = rB1 * LTS + lj0;  offB2 = rB2 * LTS + lj0;
        #pragma unroll
        for (int rr = 0; rr < 4; ++rr) {
            int base = (li0 + rr) * LTS + lj0;
            offC[rr] = base;
            int ol = base - 4;  if (ol < 0) ol = 0;
            int orr = base + 4; if (orr > LDSE - 4) orr = LDSE - 4;
            offL[rr] = ol; offR[rr] = orr;
        }
        int si = (WOFF - ri0) - li0, sj = (WOFF - rj0) - lj0;
        if (si >= 0 && si < 4 && sj >= 0 && sj < 4) smask = 1u << (si * 4 + sj);
    }

    bool mvalid = false; int mlds = 0; float* mout = nullptr;
    if (tid < NM) {
        int mc = meas[tid];
        int mi = ((mc >> 9)    - ox) & NMASK;
        int mj = ((mc & NMASK) - oy) & NMASK;
        int li = mi - ri0, lj = mj - rj0;
        mvalid = (li >= HALO && li < HALO + TI && lj >= HALO && lj < HALO + TI);
        mlds = li * LTS + lj;
        mout = out + (size_t)(r * NM + tid) * NT;
    }

    __syncthreads();

    auto step1 = [&](float (&A)[16], float (&B)[16],
                     const float* rd, float* wb, float sval, int jj) {
        if (active) {
            float t2[4], t1[4], b1a[4], b2a[4];
            float4 v;
            v = ld4(rd + offT2); t2[0]=v.x;  t2[1]=v.y;  t2[2]=v.z;  t2[3]=v.w;
            v = ld4(rd + offT1); t1[0]=v.x;  t1[1]=v.y;  t1[2]=v.z;  t1[3]=v.w;
            v = ld4(rd + offB1); b1a[0]=v.x; b1a[1]=v.y; b1a[2]=v.z; b1a[3]=v.w;
            v = ld4(rd + offB2); b2a[0]=v.x; b2a[1]=v.y; b2a[2]=v.z; b2a[3]=v.w;
            float Lw[4][4], Rw[4][4];
            #pragma unroll
            for (int rr = 0; rr < 4; ++rr) {
                v = ld4(rd + offL[rr]); Lw[rr][0]=v.x; Lw[rr][1]=v.y; Lw[rr][2]=v.z; Lw[rr][3]=v.w;
                v = ld4(rd + offR[rr]); Rw[rr][0]=v.x; Rw[rr][1]=v.y; Rw[rr][2]=v.z; Rw[rr][3]=v.w;
            }
            #pragma unroll
            for (int rr = 0; rr < 4; ++rr) {
                float w[12];
                w[0]=Lw[rr][0]; w[1]=Lw[rr][1]; w[2]=Lw[rr][2];  w[3]=Lw[rr][3];
                w[4]=B[rr*4+0]; w[5]=B[rr*4+1]; w[6]=B[rr*4+2];  w[7]=B[rr*4+3];
                w[8]=Rw[rr][0]; w[9]=Rw[rr][1]; w[10]=Rw[rr][2]; w[11]=Rw[rr][3];
                #pragma unroll
                for (int cc = 0; cc < 4; ++cc) {
                    float vm2 = (rr == 0) ? t2[cc]  : (rr == 1) ? t1[cc]  : B[(rr-2)*4+cc];
                    float vm1 = (rr == 0) ? t1[cc]  : B[(rr-1)*4+cc];
                    float vp1 = (rr == 3) ? b1a[cc] : B[(rr+1)*4+cc];
                    float vp2 = (rr == 3) ? b2a[cc] : (rr == 2) ? b1a[cc] : B[(rr+2)*4+cc];
                    float c0  = w[4+cc];
                    float lap = (16.f * (w[3+cc] + w[5+cc] + vm1 + vp1)
                                 - (w[2+cc] + w[6+cc] + vm2 + vp2)
                                 - 60.f * c0) * (1.f / 12.f);
                    float pn = 2.f * c0 - A[rr*4+cc] + K[rr*4+cc] * lap;
                    if (smask & (1u << (rr*4+cc))) pn += sval;
                    A[rr*4+cc] = pn;
                }
                st4(wb + offC[rr],
                    make_float4(A[rr*4+0], A[rr*4+1], A[rr*4+2], A[rr*4+3]));
            }
        }
        __syncthreads();
        if (mvalid) mout[jj] = wb[mlds];
    };

    for (int ph = 0; ph < NPHASE; ++ph) {
        const int J = ph * TS;
        const bool liveSelf = tile_live(tI, tJ, ph);
        if (liveSelf) {
            float sv[TS];
            #pragma unroll
            for (int s = 0; s < TS; ++s) sv[s] = 0.09f * src[J + s];
            step1(P, C, lds0, lds1, sv[0], J + 0);
            step1(C, P, lds1, lds0, sv[1], J + 1);
            step1(P, C, lds0, lds1, sv[2], J + 2);
            step1(C, P, lds1, lds0, sv[3], J + 3);
            step1(P, C, lds0, lds1, sv[4], J + 4);
            step1(C, P, lds1, lds0, sv[5], J + 5);
            step1(P, C, lds0, lds1, sv[6], J + 6);
            step1(C, P, lds1, lds0, sv[7], J + 7);
            // lds0 = f_{J+7} (valid [16,68)^2), lds1 = f_{J+6}
        }
        if (ph < NPHASE - 1) {
            float2* Wp = ((ph & 1) ? GB : GA) + (size_t)r * WCELLS;
            if (liveSelf) {       // publish interior rim (both levels packed)
                for (int q = tid; q < FRAME_N; q += NTH) {
                    int row, col;
                    if (q < FRAME_A) {
                        int rA = q / 52;
                        row = 16 + (rA < 16 ? rA : rA + 20);
                        col = 16 + (q - rA * 52);
                    } else {
                        int q2 = q - FRAME_A;
                        int rB = q2 / 32;
                        int c  = q2 - rB * 32;
                        row = 32 + rB;
                        col = 16 + (c < 16 ? c : c + 20);
                    }
                    int gw = (ri0 + row) * WW + (rj0 + col);
                    int l  = row * LTS + col;
                    float2 f2 = make_float2(lds0[l], lds1[l]);
                    u64 v; __builtin_memcpy(&v, &f2, 8);
                    __hip_atomic_store((u64*)&Wp[gw], v,
                                       __ATOMIC_RELAXED, __HIP_MEMORY_SCOPE_AGENT);
                }
                asm volatile("s_waitcnt vmcnt(0)" ::: "memory");
            }
            __syncthreads();
            if (liveSelf && tid == 0)
                __hip_atomic_store(&flags[ph * NBLK + b], 1,
                                   __ATOMIC_RELAXED, __HIP_MEMORY_SCOPE_AGENT);
            const bool liveNext = tile_live(tI, tJ, ph + 1);
            if (liveNext && tid < 9 && tid != 4) {     // spin on live neighbors
                int nti = tI + tid / 3 - 1, ntj = tJ + tid % 3 - 1;
                if ((unsigned)nti < 4u && (unsigned)ntj < 4u &&
                    tile_live(nti, ntj, ph)) {
                    int* f = &flags[ph * NBLK + ((((nti << 2) | ntj) << 4) | r)];
                    while (!__hip_atomic_load(f, __ATOMIC_RELAXED,
                                              __HIP_MEMORY_SCOPE_AGENT)) {}
                }
            }
            __syncthreads();
            if (liveNext) {       // pull halo (zero-fill dead/out-of-grid owners)
                for (int q = tid; q < HALO_N; q += NTH) {
                    int row, col;
                    if (q < HALO_TB) {
                        int rT = q / 84;
                        row = rT < 16 ? rT : rT + 52;
                        col = q - rT * 84;
                    } else {
                        int q2 = q - HALO_TB;
                        int rM = q2 / 32;
                        int c  = q2 - rM * 32;
                        row = 16 + rM;
                        col = c < 16 ? c : c + 52;
                    }
                    int nti = tI + (row < HALO ? -1 : (row >= HALO + TI ? 1 : 0));
                    int ntj = tJ + (col < HALO ? -1 : (col >= HALO + TI ? 1 : 0));
                    float v1 = 0.f, v0 = 0.f;
                    if ((unsigned)nti < 4u && (unsigned)ntj < 4u &&
                        tile_live(nti, ntj, ph)) {
                        int gw = (ri0 + row) * WW + (rj0 + col);
                        u64 v = __hip_atomic_load((const u64*)&Wp[gw],
                                __ATOMIC_RELAXED, __HIP_MEMORY_SCOPE_AGENT);
                        float2 f2; __builtin_memcpy(&f2, &v, 8);
                        v1 = f2.x; v0 = f2.y;
                    }
                    int l = row * LTS + col;
                    lds0[l] = v1;
                    lds1[l] = v0;
                }
                __syncthreads();
                if (active && !inner) {   // ring threads refill regs from LDS
                    #pragma unroll
                    for (int rr = 0; rr < 4; ++rr) {
                        float4 vc = ld4(&lds0[offC[rr]]);
                        float4 vp = ld4(&lds1[offC[rr]]);
                        C[rr*4+0]=vc.x; C[rr*4+1]=vc.y; C[rr*4+2]=vc.z; C[rr*4+3]=vc.w;
                        P[rr*4+0]=vp.x; P[rr*4+1]=vp.y; P[rr*4+2]=vp.z; P[rr*4+3]=vp.w;
                    }
                }
            }
        }
    }
}

extern "C" void kernel_launch(void* const* d_in, const int* in_sizes, int n_in,
                              void* d_out, int out_size, void* d_ws, size_t ws_size,
                              hipStream_t stream)
{
    const float* x     = (const float*)d_in[0];
    const float* src   = (const float*)d_in[1];
    const int*   meas  = (const int*)d_in[2];
    const int*   trans = (const int*)d_in[3];
    float* outp = (float*)d_out;

    int*    flags = (int*)d_ws;                         // NPHASE*NBLK ints
    float2* GA = (float2*)((char*)d_ws + 8192);
    float2* GB = GA + (size_t)NCH * WCELLS;

    hipMemsetAsync(flags, 0, NPHASE * NBLK * sizeof(int), stream);
    hipMemsetAsync(outp, 0, (size_t)out_size * sizeof(float), stream);

    persist_kernel<<<NBLK, NTH, 0, stream>>>(x, src, meas, trans, flags,
                                             GA, GB, outp);
}

// Round 9
// 78.438 us; speedup vs baseline: 1.1247x; 1.1247x over previous
//
#include <hip/hip_runtime.h>

// Wave forward: 16 channels, 208x208 window/channel, 48 steps, ONE persistent
// kernel. 6 phases x 8 substeps; boundaries sync the 3x3 tile neighborhood via
// agent-scope atomic flags; data moves as packed float2 via 64-bit relaxed
// agent atomics. Channel tiles share one XCD slot pattern (b&15 = channel).
// Liveness (support cone) gates publish/spin/pull.
// THIS ROUND: halo pull is register-batched (issue all 10 loads, then write
// LDS) so the ~900cy coherent-load latency is paid once, not 10x.

typedef unsigned long long u64;

#define GN     512
#define NMASK  511
#define NCH    16
#define NT     48
#define NM     128
#define WW     208            // window size
#define WOFF   103            // source offset inside window
#define TI     52             // tile interior
#define TS     8              // substeps per phase
#define NPHASE 6
#define HALO   16             // 2*TS
#define LT     84             // tile width (TI + 2*HALO)
#define LTS    84             // LDS row stride
#define LDSE   (LTS*LT)       // 7056
#define WCELLS (WW*WW)        // 43264
#define NTH    448            // 7 waves
#define NACT   441            // 21x21 threads x 4x4 cells = 84^2
#define NBLK   256
#define FRAME_N 2304          // interior rim cells (52^2 - 20^2)
#define FRAME_A 1664          // rows 16-31,52-67 x cols 16-67
#define HALO_N  4352          // 84^2 - 52^2
#define HALO_TB 2688          // rows 0-15,68-83 x cols 0-83
#define NPULL   10            // ceil(HALO_N / NTH)

__device__ __forceinline__ float4 ld4(const float* p) { return *(const float4*)p; }
__device__ __forceinline__ void st4(float* p, float4 v) { *(float4*)p = v; }

__device__ __forceinline__ float kcoef(const float* __restrict__ x, int gi, int gj) {
    float xp;
    if (gi < 55 || gi >= 457 || gj < 55 || gj >= 457)
        xp = 1e-6f;                                   // ABC pad
    else if (gi >= 128 && gi < 384 && gj >= 128 && gj < 384)
        xp = x[(gi - 128) * 256 + (gj - 128)];
    else
        xp = 1.5f;                                    // bg pad
    float t = 0.2f * xp;
    return t * t;
}

// support-cone distance of a tile's 84^2 region to the source (channel-indep.)
__device__ __forceinline__ int tile_sdist(int ti, int tj) {
    int lo = ti * TI - HALO, hi = lo + LT - 1;
    int di = WOFF < lo ? lo - WOFF : (WOFF > hi ? WOFF - hi : 0);
    lo = tj * TI - HALO; hi = lo + LT - 1;
    int dj = WOFF < lo ? lo - WOFF : (WOFF > hi ? WOFF - hi : 0);
    return di > dj ? di : dj;
}
__device__ __forceinline__ bool tile_live(int ti, int tj, int ph) {
    return tile_sdist(ti, tj) <= 2 * (ph * TS + TS) + 4;
}

__global__ __launch_bounds__(NTH, 1)
void persist_kernel(const float* __restrict__ x,
                    const float* __restrict__ src,
                    const int* __restrict__ meas,
                    const int* __restrict__ trans,
                    int* __restrict__ flags,
                    float2* __restrict__ GA, float2* __restrict__ GB,
                    float* __restrict__ out)
{
    __shared__ float lds0[LDSE];
    __shared__ float lds1[LDSE];
    const int tid  = threadIdx.x;
    const int b    = blockIdx.x;
    const int r    = b & 15;          // channel -> all its tiles share b%8 (XCD)
    const int tile = b >> 4;
    const int tI   = tile >> 2, tJ = tile & 3;
    const int ri0  = tI * TI - HALO;
    const int rj0  = tJ * TI - HALO;

    const bool active = tid < NACT;
    const int ty = tid / 21, tx = tid - 21 * (tid / 21);
    const int li0 = 4 * ty, lj0 = 4 * tx;
    const bool inner = active && tx >= 4 && tx <= 16 && ty >= 4 && ty <= 16;

    // zero BOTH buffers (dead->live blocks rely on pristine-zero LDS)
    for (int q = tid; q < LDSE / 4; q += NTH) {
        st4(&lds0[q * 4], make_float4(0.f, 0.f, 0.f, 0.f));
        st4(&lds1[q * 4], make_float4(0.f, 0.f, 0.f, 0.f));
    }

    const int trv = trans[r];
    const int ox = (trv >> 9) - WOFF, oy = (trv & NMASK) - WOFF;

    float C[16], P[16], K[16];
    #pragma unroll
    for (int i = 0; i < 16; ++i) { C[i] = 0.f; P[i] = 0.f; K[i] = 0.f; }

    int offT2 = 0, offT1 = 0, offB1 = 0, offB2 = 0;
    int offL[4] = {0,0,0,0}, offR[4] = {0,0,0,0}, offC[4] = {0,0,0,0};
    unsigned smask = 0;
    if (active) {
        #pragma unroll
        for (int rr = 0; rr < 4; ++rr) {
            int wr = ri0 + li0 + rr;
            #pragma unroll
            for (int cc = 0; cc < 4; ++cc) {
                int wc = rj0 + lj0 + cc;
                K[rr*4+cc] = kcoef(x, (ox + wr) & NMASK, (oy + wc) & NMASK);
            }
        }
        int rT2 = li0 - 2 < 0 ? 0 : li0 - 2;
        int rT1 = li0 - 1 < 0 ? 0 : li0 - 1;
        int rB1 = li0 + 4 > LT - 1 ? LT - 1 : li0 + 4;
        int rB2 = li0 + 5 > LT - 1 ? LT - 1 : li0 + 5;
        offT2 = rT2 * LTS + lj0;  offT1 = rT1 * LTS + lj0;
        offB1 = rB1 * LTS + lj0;  offB2 = rB2 * LTS + lj0;
        #pragma unroll
        for (int rr = 0; rr < 4; ++rr) {
            int base = (li0 + rr) * LTS + lj0;
            offC[rr] = base;
            int ol = base - 4;  if (ol < 0) ol = 0;
            int orr = base + 4; if (orr > LDSE - 4) orr = LDSE - 4;
            offL[rr] = ol; offR[rr] = orr;
        }
        int si = (WOFF - ri0) - li0, sj = (WOFF - rj0) - lj0;
        if (si >= 0 && si < 4 && sj >= 0 && sj < 4) smask = 1u << (si * 4 + sj);
    }

    bool mvalid = false; int mlds = 0; float* mout = nullptr;
    if (tid < NM) {
        int mc = meas[tid];
        int mi = ((mc >> 9)    - ox) & NMASK;
        int mj = ((mc & NMASK) - oy) & NMASK;
        int li = mi - ri0, lj = mj - rj0;
        mvalid = (li >= HALO && li < HALO + TI && lj >= HALO && lj < HALO + TI);
        mlds = li * LTS + lj;
        mout = out + (size_t)(r * NM + tid) * NT;
    }

    __syncthreads();

    auto step1 = [&](float (&A)[16], float (&B)[16],
                     const float* rd, float* wb, float sval, int jj) {
        if (active) {
            float t2[4], t1[4], b1a[4], b2a[4];
            float4 v;
            v = ld4(rd + offT2); t2[0]=v.x;  t2[1]=v.y;  t2[2]=v.z;  t2[3]=v.w;
            v = ld4(rd + offT1); t1[0]=v.x;  t1[1]=v.y;  t1[2]=v.z;  t1[3]=v.w;
            v = ld4(rd + offB1); b1a[0]=v.x; b1a[1]=v.y; b1a[2]=v.z; b1a[3]=v.w;
            v = ld4(rd + offB2); b2a[0]=v.x; b2a[1]=v.y; b2a[2]=v.z; b2a[3]=v.w;
            float Lw[4][4], Rw[4][4];
            #pragma unroll
            for (int rr = 0; rr < 4; ++rr) {
                v = ld4(rd + offL[rr]); Lw[rr][0]=v.x; Lw[rr][1]=v.y; Lw[rr][2]=v.z; Lw[rr][3]=v.w;
                v = ld4(rd + offR[rr]); Rw[rr][0]=v.x; Rw[rr][1]=v.y; Rw[rr][2]=v.z; Rw[rr][3]=v.w;
            }
            #pragma unroll
            for (int rr = 0; rr < 4; ++rr) {
                float w[12];
                w[0]=Lw[rr][0]; w[1]=Lw[rr][1]; w[2]=Lw[rr][2];  w[3]=Lw[rr][3];
                w[4]=B[rr*4+0]; w[5]=B[rr*4+1]; w[6]=B[rr*4+2];  w[7]=B[rr*4+3];
                w[8]=Rw[rr][0]; w[9]=Rw[rr][1]; w[10]=Rw[rr][2]; w[11]=Rw[rr][3];
                #pragma unroll
                for (int cc = 0; cc < 4; ++cc) {
                    float vm2 = (rr == 0) ? t2[cc]  : (rr == 1) ? t1[cc]  : B[(rr-2)*4+cc];
                    float vm1 = (rr == 0) ? t1[cc]  : B[(rr-1)*4+cc];
                    float vp1 = (rr == 3) ? b1a[cc] : B[(rr+1)*4+cc];
                    float vp2 = (rr == 3) ? b2a[cc] : (rr == 2) ? b1a[cc] : B[(rr+2)*4+cc];
                    float c0  = w[4+cc];
                    float lap = (16.f * (w[3+cc] + w[5+cc] + vm1 + vp1)
                                 - (w[2+cc] + w[6+cc] + vm2 + vp2)
                                 - 60.f * c0) * (1.f / 12.f);
                    float pn = 2.f * c0 - A[rr*4+cc] + K[rr*4+cc] * lap;
                    if (smask & (1u << (rr*4+cc))) pn += sval;
                    A[rr*4+cc] = pn;
                }
                st4(wb + offC[rr],
                    make_float4(A[rr*4+0], A[rr*4+1], A[rr*4+2], A[rr*4+3]));
            }
        }
        __syncthreads();
        if (mvalid) mout[jj] = wb[mlds];
    };

    for (int ph = 0; ph < NPHASE; ++ph) {
        const int J = ph * TS;
        const bool liveSelf = tile_live(tI, tJ, ph);
        if (liveSelf) {
            float sv[TS];
            #pragma unroll
            for (int s = 0; s < TS; ++s) sv[s] = 0.09f * src[J + s];
            step1(P, C, lds0, lds1, sv[0], J + 0);
            step1(C, P, lds1, lds0, sv[1], J + 1);
            step1(P, C, lds0, lds1, sv[2], J + 2);
            step1(C, P, lds1, lds0, sv[3], J + 3);
            step1(P, C, lds0, lds1, sv[4], J + 4);
            step1(C, P, lds1, lds0, sv[5], J + 5);
            step1(P, C, lds0, lds1, sv[6], J + 6);
            step1(C, P, lds1, lds0, sv[7], J + 7);
            // lds0 = f_{J+7} (valid [16,68)^2), lds1 = f_{J+6}
        }
        if (ph < NPHASE - 1) {
            float2* Wp = ((ph & 1) ? GB : GA) + (size_t)r * WCELLS;
            if (liveSelf) {       // publish interior rim (both levels packed)
                for (int q = tid; q < FRAME_N; q += NTH) {
                    int row, col;
                    if (q < FRAME_A) {
                        int rA = q / 52;
                        row = 16 + (rA < 16 ? rA : rA + 20);
                        col = 16 + (q - rA * 52);
                    } else {
                        int q2 = q - FRAME_A;
                        int rB = q2 / 32;
                        int c  = q2 - rB * 32;
                        row = 32 + rB;
                        col = 16 + (c < 16 ? c : c + 20);
                    }
                    int gw = (ri0 + row) * WW + (rj0 + col);
                    int l  = row * LTS + col;
                    float2 f2 = make_float2(lds0[l], lds1[l]);
                    u64 v; __builtin_memcpy(&v, &f2, 8);
                    __hip_atomic_store((u64*)&Wp[gw], v,
                                       __ATOMIC_RELAXED, __HIP_MEMORY_SCOPE_AGENT);
                }
                asm volatile("s_waitcnt vmcnt(0)" ::: "memory");
            }
            __syncthreads();
            if (liveSelf && tid == 0)
                __hip_atomic_store(&flags[ph * NBLK + b], 1,
                                   __ATOMIC_RELAXED, __HIP_MEMORY_SCOPE_AGENT);
            const bool liveNext = tile_live(tI, tJ, ph + 1);
            if (liveNext && tid < 9 && tid != 4) {     // spin on live neighbors
                int nti = tI + tid / 3 - 1, ntj = tJ + tid % 3 - 1;
                if ((unsigned)nti < 4u && (unsigned)ntj < 4u &&
                    tile_live(nti, ntj, ph)) {
                    int* f = &flags[ph * NBLK + ((((nti << 2) | ntj) << 4) | r)];
                    while (!__hip_atomic_load(f, __ATOMIC_RELAXED,
                                              __HIP_MEMORY_SCOPE_AGENT)) {}
                }
            }
            __syncthreads();
            if (liveNext) {
                // ---- batched pull: issue ALL loads first (statically indexed
                // registers), then write LDS -> one latency, not NPULL.
                u64 vv[NPULL]; int ll[NPULL];
                #pragma unroll
                for (int k = 0; k < NPULL; ++k) {
                    vv[k] = 0; ll[k] = -1;
                    int q = tid + k * NTH;
                    if (q < HALO_N) {
                        int row, col;
                        if (q < HALO_TB) {
                            int rT = q / 84;
                            row = rT < 16 ? rT : rT + 52;
                            col = q - rT * 84;
                        } else {
                            int q2 = q - HALO_TB;
                            int rM = q2 / 32;
                            int c  = q2 - rM * 32;
                            row = 16 + rM;
                            col = c < 16 ? c : c + 52;
                        }
                        ll[k] = row * LTS + col;
                        int nti = tI + (row < HALO ? -1 : (row >= HALO + TI ? 1 : 0));
                        int ntj = tJ + (col < HALO ? -1 : (col >= HALO + TI ? 1 : 0));
                        if ((unsigned)nti < 4u && (unsigned)ntj < 4u &&
                            tile_live(nti, ntj, ph)) {
                            int gw = (ri0 + row) * WW + (rj0 + col);
                            vv[k] = __hip_atomic_load((const u64*)&Wp[gw],
                                    __ATOMIC_RELAXED, __HIP_MEMORY_SCOPE_AGENT);
                        }
                    }
                }
                #pragma unroll
                for (int k = 0; k < NPULL; ++k) {
                    if (ll[k] >= 0) {
                        float2 f2; __builtin_memcpy(&f2, &vv[k], 8);
                        lds0[ll[k]] = f2.x;
                        lds1[ll[k]] = f2.y;
                    }
                }
                __syncthreads();
                if (active && !inner) {   // ring threads refill regs from LDS
                    #pragma unroll
                    for (int rr = 0; rr < 4; ++rr) {
                        float4 vc = ld4(&lds0[offC[rr]]);
                        float4 vp = ld4(&lds1[offC[rr]]);
                        C[rr*4+0]=vc.x; C[rr*4+1]=vc.y; C[rr*4+2]=vc.z; C[rr*4+3]=vc.w;
                        P[rr*4+0]=vp.x; P[rr*4+1]=vp.y; P[rr*4+2]=vp.z; P[rr*4+3]=vp.w;
                    }
                }
            }
        }
    }
}

extern "C" void kernel_launch(void* const* d_in, const int* in_sizes, int n_in,
                              void* d_out, int out_size, void* d_ws, size_t ws_size,
                              hipStream_t stream)
{
    const float* x     = (const float*)d_in[0];
    const float* src   = (const float*)d_in[1];
    const int*   meas  = (const int*)d_in[2];
    const int*   trans = (const int*)d_in[3];
    float* outp = (float*)d_out;

    int*    flags = (int*)d_ws;                         // NPHASE*NBLK ints
    float2* GA = (float2*)((char*)d_ws + 8192);
    float2* GB = GA + (size_t)NCH * WCELLS;

    hipMemsetAsync(flags, 0, NPHASE * NBLK * sizeof(int), stream);
    hipMemsetAsync(outp, 0, (size_t)out_size * sizeof(float), stream);

    persist_kernel<<<NBLK, NTH, 0, stream>>>(x, src, meas, trans, flags,
                                             GA, GB, outp);
}